// Round 17
// baseline (438.496 us; speedup 1.0000x reference)
//
#include <hip/hip_runtime.h>
#include <hip/hip_bf16.h>

// Problem constants (from reference)
constexpr int NN = 90000;   // total nodes
constexpr int NP = 60000;   // paper nodes
constexpr int NM = 30000;   // mesh nodes
constexpr int ET = 2000000; // train edges
constexpr int ED = 400000;  // decode edges (each of pos/neg)
constexpr int TWO_NN = 2 * NN;

// Binned CSR build parameters (512-key buckets)
constexpr int BKT_SH  = 9;                           // 512 keys per bucket
constexpr int NB_BKT  = (TWO_NN + 511) >> BKT_SH;    // 352 buckets
constexpr int BKT_CAP = 6400;                        // mean 5683, +9.5 sigma
constexpr int TILE    = 2048;                        // edges per binning tile
constexpr int N_TILES = (ET + TILE - 1) / TILE;      // 977

__device__ __forceinline__ float bflo(unsigned int u) {
    union { unsigned int i; float f; } c;
    c.i = u << 16;
    return c.f;
}
__device__ __forceinline__ float bfhi(unsigned int u) {
    union { unsigned int i; float f; } c;
    c.i = u & 0xffff0000u;
    return c.f;
}
__device__ __forceinline__ unsigned short f2bf(float f) {
    union { float f; unsigned int i; } c;
    c.f = f;
    unsigned int x = c.i;
    return (unsigned short)((x + 0x7FFFu + ((x >> 16) & 1u)) >> 16);
}

// ---------------------------------------------------------------------------
__global__ void init_kernel(const int* __restrict__ tei, int* __restrict__ gcur,
                            int* __restrict__ dflag) {
    int b = blockIdx.x * blockDim.x + threadIdx.x;
    if (b < NB_BKT) gcur[b] = b * BKT_CAP;
    if (b == 0) {
        int allzero = 1;
        for (int i = 0; i < 16; i++)
            if (tei[2 * i + 1] != 0) allzero = 0;
        dflag[0] = allzero; // 1 => int64 => index shift 1
    }
}

// ---------------------------------------------------------------------------
// Pass A: bin edges into per-bucket pair arrays; per-wave privatized
// histograms + cursors (R16).
__global__ void __launch_bounds__(256) binA_kernel(
        const int* __restrict__ ei, const int* __restrict__ et,
        const int* __restrict__ dflag, int* __restrict__ gcur,
        int2* __restrict__ pairs) {
    __shared__ int histw[4][NB_BKT];
    __shared__ int wbase[4][NB_BKT];
    __shared__ int tot[NB_BKT];
    __shared__ int excl[NB_BKT];
    __shared__ int gbase[NB_BKT];
    __shared__ int scn[256];
    __shared__ int2 tbuf[TILE];
    int t = threadIdx.x;
    int w = t >> 6;
    int tile0 = blockIdx.x * TILE;
    int tcount = ET - tile0;
    if (tcount > TILE) tcount = TILE;
    for (int i = t; i < 4 * NB_BKT; i += 256) ((int*)histw)[i] = 0;
    __syncthreads();
    int sft = dflag[0];
    int myk[8], mys[8];
#pragma unroll
    for (int q = 0; q < 8; q++) {
        int li = q * 256 + t;
        myk[q] = -1;
        if (li < tcount) {
            int e = tile0 + li;
            int s = ei[(size_t)e << sft];
            int d = ei[(size_t)(ET + e) << sft];
            int r = et[(size_t)e << sft];
            int key = r * NN + d;
            myk[q] = key;
            mys[q] = s;
            atomicAdd(&histw[w][key >> BKT_SH], 1);
        }
    }
    __syncthreads();
    for (int i = t; i < NB_BKT; i += 256) {
        int h0 = histw[0][i], h1 = histw[1][i], h2 = histw[2][i], h3 = histw[3][i];
        wbase[0][i] = 0;
        wbase[1][i] = h0;
        wbase[2][i] = h0 + h1;
        wbase[3][i] = h0 + h1 + h2;
        tot[i] = h0 + h1 + h2 + h3;
    }
    __syncthreads();
    int v0 = (t < NB_BKT / 2) ? tot[2 * t] : 0;
    int v1 = (t < NB_BKT / 2) ? tot[2 * t + 1] : 0;
    int s = v0 + v1;
    scn[t] = s;
    __syncthreads();
    for (int st = 1; st < 256; st <<= 1) {
        int u = (t >= st) ? scn[t - st] : 0;
        __syncthreads();
        scn[t] += u;
        __syncthreads();
    }
    int base = scn[t] - s;
    if (t < NB_BKT / 2) {
        excl[2 * t] = base;
        excl[2 * t + 1] = base + v0;
    }
    __syncthreads();
    for (int i = t; i < NB_BKT; i += 256) {
        int e0 = excl[i];
        wbase[0][i] += e0;
        wbase[1][i] += e0;
        wbase[2][i] += e0;
        wbase[3][i] += e0;
        histw[0][i] = 0; histw[1][i] = 0; histw[2][i] = 0; histw[3][i] = 0;
    }
    __syncthreads();
#pragma unroll
    for (int q = 0; q < 8; q++) {
        if (myk[q] >= 0) {
            int b = myk[q] >> BKT_SH;
            int p = wbase[w][b] + atomicAdd(&histw[w][b], 1);
            tbuf[p] = make_int2(myk[q], mys[q]);
        }
    }
    __syncthreads();
    for (int i = t; i < NB_BKT; i += 256)
        if (tot[i] > 0) gbase[i] = atomicAdd(&gcur[i], tot[i]);
    __syncthreads();
    for (int i = t; i < tcount; i += 256) {
        int2 p = tbuf[i];
        int b = p.x >> BKT_SH;
        int gpos = gbase[b] + (i - excl[b]);
        int cap = (b + 1) * BKT_CAP - 1;
        pairs[gpos < cap ? gpos : cap] = p;
    }
}

// ---------------------------------------------------------------------------
// Pass B (merged hist+place): per-bucket histogram + scan -> off/endo/inv,
// then place into padded CSR.
__global__ void __launch_bounds__(256) histplace_kernel(
        const int* __restrict__ gcur, const int2* __restrict__ pairs,
        int* __restrict__ off, int* __restrict__ endo, float* __restrict__ inv,
        int* __restrict__ csr) {
    __shared__ int kh[512];
    __shared__ int scn[256];
    int b = blockIdx.x;
    int t = threadIdx.x;
    int beg = b * BKT_CAP, end = gcur[b];
    for (int i = t; i < 512; i += 256) kh[i] = 0;
    __syncthreads();
    for (int i = beg + t; i < end; i += 256)
        atomicAdd(&kh[pairs[i].x & 511], 1);
    __syncthreads();
    int v[2];
    int s = 0;
#pragma unroll
    for (int q = 0; q < 2; q++) {
        v[q] = kh[t * 2 + q];
        s += v[q];
    }
    scn[t] = s;
    __syncthreads();
    for (int st = 1; st < 256; st <<= 1) {
        int u = (t >= st) ? scn[t - st] : 0;
        __syncthreads();
        scn[t] += u;
        __syncthreads();
    }
    int run = beg + scn[t] - s;
    int kbase = b << BKT_SH;
    int kc[2];
#pragma unroll
    for (int q = 0; q < 2; q++) {
        int key = kbase + t * 2 + q;
        if (key < TWO_NN) {
            off[key] = run;
            endo[key] = run + v[q];
            inv[key] = 1.0f / (float)(v[q] > 1 ? v[q] : 1);
        }
        kc[q] = run;
        run += v[q];
    }
    __syncthreads();
#pragma unroll
    for (int q = 0; q < 2; q++) kh[t * 2 + q] = kc[q];
    __syncthreads();
    for (int i = beg + t; i < end; i += 256) {
        int2 p = pairs[i];
        int pos = atomicAdd(&kh[p.x & 511], 1);
        csr[pos] = p.y;
    }
}

// ---------------------------------------------------------------------------
// Fused input embed -> feature-sliced bf16 table xc[2][NN][8].
__global__ void __launch_bounds__(256) embed2_kernel(
        const float* __restrict__ Xp, const float* __restrict__ Xm,
        const float* __restrict__ Wp, const float* __restrict__ bp,
        const float* __restrict__ Wm, const float* __restrict__ bm,
        unsigned short* __restrict__ xc) {
    __shared__ float Wl[4096 + 32];
    for (int i = threadIdx.x; i < 2048; i += 256) {
        Wl[i] = Wp[i];
        Wl[2048 + i] = Wm[i];
    }
    if (threadIdx.x < 16) {
        Wl[4096 + threadIdx.x] = bp[threadIdx.x];
        Wl[4112 + threadIdx.x] = bm[threadIdx.x];
    }
    __syncthreads();
    int n = blockIdx.x * 256 + threadIdx.x;
    if (n >= NN) return;
    const float* X;
    const float* Ws;
    const float* Bs;
    if (n < NP) { X = Xp + (size_t)n * 128; Ws = Wl; Bs = Wl + 4096; }
    else        { X = Xm + (size_t)(n - NP) * 128; Ws = Wl + 2048; Bs = Wl + 4112; }
    float acc[16];
#pragma unroll
    for (int j = 0; j < 16; j++) acc[j] = Bs[j];
    const float4* row = (const float4*)X;
    for (int k4 = 0; k4 < 32; k4++) {
        float4 xv = row[k4];
        int k = k4 * 4;
#pragma unroll
        for (int j = 0; j < 16; j++) {
            float a = acc[j];
            a = fmaf(xv.x, Ws[(k + 0) * 16 + j], a);
            a = fmaf(xv.y, Ws[(k + 1) * 16 + j], a);
            a = fmaf(xv.z, Ws[(k + 2) * 16 + j], a);
            a = fmaf(xv.w, Ws[(k + 3) * 16 + j], a);
            acc[j] = a;
        }
    }
#pragma unroll
    for (int sl = 0; sl < 2; sl++) {
        ushort4 u0, u1;
        u0.x = f2bf(acc[sl * 8 + 0]); u0.y = f2bf(acc[sl * 8 + 1]);
        u0.z = f2bf(acc[sl * 8 + 2]); u0.w = f2bf(acc[sl * 8 + 3]);
        u1.x = f2bf(acc[sl * 8 + 4]); u1.y = f2bf(acc[sl * 8 + 5]);
        u1.z = f2bf(acc[sl * 8 + 6]); u1.w = f2bf(acc[sl * 8 + 7]);
        unsigned short* p = xc + ((size_t)sl * NN + n) * 8;
        *(ushort4*)p = u0;
        *(ushort4*)(p + 4) = u1;
    }
}

// ---------------------------------------------------------------------------
// All 4 layers' weight prep in ONE launch (Wbuf4 stride 3200 per layer).
__global__ void prep_all_kernel(
        const float* __restrict__ ba0, const float* __restrict__ co0,
        const float* __restrict__ ro0, const float* __restrict__ bi0,
        const float* __restrict__ ba1, const float* __restrict__ co1,
        const float* __restrict__ ro1, const float* __restrict__ bi1,
        const float* __restrict__ ba2, const float* __restrict__ co2,
        const float* __restrict__ ro2, const float* __restrict__ bi2,
        const float* __restrict__ ba3, const float* __restrict__ co3,
        const float* __restrict__ ro3, const float* __restrict__ bi3,
        float* __restrict__ Wbuf4) {
    int l = blockIdx.x;
    const float* bases; const float* comp; const float* root; const float* bias;
    if (l == 0)      { bases = ba0; comp = co0; root = ro0; bias = bi0; }
    else if (l == 1) { bases = ba1; comp = co1; root = ro1; bias = bi1; }
    else if (l == 2) { bases = ba2; comp = co2; root = ro2; bias = bi2; }
    else             { bases = ba3; comp = co3; root = ro3; bias = bi3; }
    int din = (l == 0) ? 16 : 32;
    int dout = (l == 3) ? 16 : 32;
    int sz = din * dout;
    float* W = Wbuf4 + l * 3200;
    for (int i = threadIdx.x; i < sz; i += 256) {
        float b0 = bases[i];
        float b1 = bases[sz + i];
        float b2 = bases[2 * sz + i];
        float b3 = bases[3 * sz + i];
        for (int r = 0; r < 2; r++) {
            W[r * sz + i] = comp[r * 4 + 0] * b0 + comp[r * 4 + 1] * b1 +
                            comp[r * 4 + 2] * b2 + comp[r * 4 + 3] * b3;
        }
        W[2 * sz + i] = root[i];
    }
    if (threadIdx.x < dout) W[3 * sz + threadIdx.x] = bias[threadIdx.x];
}

// ---------------------------------------------------------------------------
// XCD-sliced gather: slice = (blockIdx%8)>>2 so (under round-robin block->XCD
// dispatch) XCDs 0-3 only touch slice 0's 2.88 MB chunk, 4-7 slice 1 —
// gathers become L2-resident instead of cross-XCD HBM replication (R13-R16:
// layer pinned at 46 MB compulsory random-line fetch).
// agg layout: [slice][rel][node][F] fp32 (dense writes).
template <int DIN>
__global__ void __launch_bounds__(256) gather_slice_kernel(
        const int* __restrict__ off, const int* __restrict__ endo,
        const int* __restrict__ csr, const unsigned short* __restrict__ xc,
        float* __restrict__ agg) {
    constexpr int F = DIN / 2;     // features per slice
    constexpr int LPS = F / 8;     // 16B lanes per (dst,rel) group
    constexpr int GPB = 256 / LPS; // groups per block
    int b = blockIdx.x;
    int slice = (b & 7) >> 2;
    int kb = (b >> 3) * 4 + (b & 3);
    int gi = kb * GPB + (int)threadIdx.x / LPS;
    if (gi >= TWO_NN) return;
    int lane = (int)threadIdx.x % LPS;
    const unsigned short* hp = xc + (size_t)slice * NN * F + lane * 8;
    int beg = off[gi], end = endo[gi];
    float a0[8] = {0, 0, 0, 0, 0, 0, 0, 0};
    float a1[8] = {0, 0, 0, 0, 0, 0, 0, 0};
    int k = beg;
    for (; k + 1 < end; k += 2) {
        int s0 = csr[k];
        int s1 = csr[k + 1];
        uint4 u0 = *(const uint4*)(hp + (size_t)s0 * F);
        uint4 u1 = *(const uint4*)(hp + (size_t)s1 * F);
        a0[0] += bflo(u0.x); a0[1] += bfhi(u0.x);
        a0[2] += bflo(u0.y); a0[3] += bfhi(u0.y);
        a0[4] += bflo(u0.z); a0[5] += bfhi(u0.z);
        a0[6] += bflo(u0.w); a0[7] += bfhi(u0.w);
        a1[0] += bflo(u1.x); a1[1] += bfhi(u1.x);
        a1[2] += bflo(u1.y); a1[3] += bfhi(u1.y);
        a1[4] += bflo(u1.z); a1[5] += bfhi(u1.z);
        a1[6] += bflo(u1.w); a1[7] += bfhi(u1.w);
    }
    if (k < end) {
        uint4 u0 = *(const uint4*)(hp + (size_t)csr[k] * F);
        a0[0] += bflo(u0.x); a0[1] += bfhi(u0.x);
        a0[2] += bflo(u0.y); a0[3] += bfhi(u0.y);
        a0[4] += bflo(u0.z); a0[5] += bfhi(u0.z);
        a0[6] += bflo(u0.w); a0[7] += bfhi(u0.w);
    }
    int rel = gi >= NN ? 1 : 0;
    int d = gi - rel * NN;
    float* ap = agg + (((size_t)slice * 2 + rel) * NN + d) * F + lane * 8;
    *(float4*)ap = make_float4(a0[0] + a1[0], a0[1] + a1[1],
                               a0[2] + a1[2], a0[3] + a1[3]);
    *(float4*)(ap + 4) = make_float4(a0[4] + a1[4], a0[5] + a1[5],
                                     a0[6] + a1[6], a0[7] + a1[7]);
}

// ---------------------------------------------------------------------------
// Combine: out[n] = relu?( x[n]@root + b + m0@W0 + m1@W1 ), all dense reads.
// ZOUT=1 writes plain bf16 z rows (for decode); else sliced layout for the
// next layer's gather.
template <int DIN, int DOUT, int RELU, int ZOUT>
__global__ void __launch_bounds__(256) combine_kernel(
        const unsigned short* __restrict__ xc_in, const float* __restrict__ agg,
        const float* __restrict__ inv, const float* __restrict__ Wbuf,
        unsigned short* __restrict__ xc_out) {
    constexpr int F = DIN / 2;
    constexpr int SZ = DIN * DOUT;
    constexpr int CPN = DOUT / 4;
    constexpr int NPB = 256 / CPN;
    constexpr int XSST = DIN + 4;
    constexpr int AGST = 2 * DIN + 4;
    __shared__ float Wl[3 * SZ + DOUT];
    __shared__ float xs[NPB * XSST];
    __shared__ float ag[NPB * AGST];
    int t = threadIdx.x;
    for (int i = t; i < 3 * SZ + DOUT; i += 256) Wl[i] = Wbuf[i];
    int n0 = blockIdx.x * NPB;
    // stage x rows (bf16 -> fp32), 16B chunks
    constexpr int CH = DIN / 8;
    for (int i = t; i < NPB * CH; i += 256) {
        int node = i / CH, c = i % CH;
        int n = n0 + node;
        if (n < NN) {
            int slice = c / (F / 8);
            int cc = c % (F / 8);
            uint4 u = *(const uint4*)(xc_in + ((size_t)slice * NN + n) * F + cc * 8);
            float* xp = xs + node * XSST + slice * F + cc * 8;
            xp[0] = bflo(u.x); xp[1] = bfhi(u.x);
            xp[2] = bflo(u.y); xp[3] = bfhi(u.y);
            xp[4] = bflo(u.z); xp[5] = bfhi(u.z);
            xp[6] = bflo(u.w); xp[7] = bfhi(u.w);
        }
    }
    // stage agg rows (fp32), float4 chunks
    constexpr int QPR = F / 4;
    constexpr int CH2 = 2 * DIN / 4;
    for (int i = t; i < NPB * CH2; i += 256) {
        int node = i / CH2, c = i % CH2;
        int n = n0 + node;
        if (n < NN) {
            int slice = c / (2 * QPR);
            int rem = c % (2 * QPR);
            int rel = rem / QPR;
            int q = rem % QPR;
            float4 v = *(const float4*)(
                agg + (((size_t)slice * 2 + rel) * NN + n) * F + q * 4);
            float* gp = ag + node * AGST + rel * DIN + slice * F + q * 4;
            gp[0] = v.x; gp[1] = v.y; gp[2] = v.z; gp[3] = v.w;
        }
    }
    __syncthreads();
    int node = t / CPN;
    int j0 = (t % CPN) * 4;
    int d2 = n0 + node;
    if (d2 >= NN) return;
    float iv0 = inv[d2], iv1 = inv[NN + d2];
    float acc[4];
#pragma unroll
    for (int jj = 0; jj < 4; jj++) acc[jj] = Wl[3 * SZ + j0 + jj];
#pragma unroll
    for (int k = 0; k < DIN; k++) {
        float xv = xs[node * XSST + k];
        float m0 = ag[node * AGST + k] * iv0;
        float m1 = ag[node * AGST + DIN + k] * iv1;
        const float* w0 = &Wl[k * DOUT + j0];
        const float* w1 = &Wl[SZ + k * DOUT + j0];
        const float* wr = &Wl[2 * SZ + k * DOUT + j0];
#pragma unroll
        for (int jj = 0; jj < 4; jj++) {
            acc[jj] = fmaf(xv, wr[jj], acc[jj]);
            acc[jj] = fmaf(m0, w0[jj], acc[jj]);
            acc[jj] = fmaf(m1, w1[jj], acc[jj]);
        }
    }
    if (RELU) {
#pragma unroll
        for (int jj = 0; jj < 4; jj++) acc[jj] = fmaxf(acc[jj], 0.0f);
    }
    ushort4 ub;
    ub.x = f2bf(acc[0]); ub.y = f2bf(acc[1]);
    ub.z = f2bf(acc[2]); ub.w = f2bf(acc[3]);
    if (ZOUT) {
        *(ushort4*)(xc_out + (size_t)d2 * DOUT + j0) = ub;
    } else {
        constexpr int FO = DOUT / 2;
        int so = j0 >= FO ? 1 : 0;
        *(ushort4*)(xc_out + ((size_t)so * NN + d2) * FO + (j0 - so * FO)) = ub;
    }
}

// ---------------------------------------------------------------------------
// Fused decode on plain bf16 z: out[i] = dot( z[s]@Wd_r + bd_r , z[d] ).
__global__ void __launch_bounds__(256) decode_fused_kernel(
        const unsigned short* __restrict__ zbf,
        const float* __restrict__ Wd0, const float* __restrict__ bd0,
        const float* __restrict__ Wd1, const float* __restrict__ bd1,
        const int* __restrict__ pei, const int* __restrict__ pet,
        const int* __restrict__ nei, const int* __restrict__ net_,
        float* __restrict__ out, const int* __restrict__ dflag) {
    __shared__ float W[2][256];
    __shared__ float B[2][16];
    for (int i = threadIdx.x; i < 256; i += 256) {
        W[0][i] = Wd0[i];
        W[1][i] = Wd1[i];
    }
    if (threadIdx.x < 16) {
        B[0][threadIdx.x] = bd0[threadIdx.x];
        B[1][threadIdx.x] = bd1[threadIdx.x];
    }
    __syncthreads();
    int i = blockIdx.x * 256 + threadIdx.x;
    if (i >= 2 * ED) return;
    int sft = dflag[0];
    const int* ei;
    const int* et;
    int e;
    if (i < ED) { ei = pei; et = pet; e = i; }
    else        { ei = nei; et = net_; e = i - ED; }
    int s = ei[(size_t)e << sft];
    int d = ei[(size_t)(ED + e) << sft];
    int r = et[(size_t)e << sft];
    float zs[16], zd[16];
    const uint4* sp = (const uint4*)(zbf + ((size_t)s << 4));
    const uint4* dp = (const uint4*)(zbf + ((size_t)d << 4));
#pragma unroll
    for (int h = 0; h < 2; h++) {
        uint4 us = sp[h];
        uint4 ud = dp[h];
        int o8 = h * 8;
        zs[o8 + 0] = bflo(us.x); zs[o8 + 1] = bfhi(us.x);
        zs[o8 + 2] = bflo(us.y); zs[o8 + 3] = bfhi(us.y);
        zs[o8 + 4] = bflo(us.z); zs[o8 + 5] = bfhi(us.z);
        zs[o8 + 6] = bflo(us.w); zs[o8 + 7] = bfhi(us.w);
        zd[o8 + 0] = bflo(ud.x); zd[o8 + 1] = bfhi(ud.x);
        zd[o8 + 2] = bflo(ud.y); zd[o8 + 3] = bfhi(ud.y);
        zd[o8 + 4] = bflo(ud.z); zd[o8 + 5] = bfhi(ud.z);
        zd[o8 + 6] = bflo(ud.w); zd[o8 + 7] = bfhi(ud.w);
    }
    const float* Wr = W[r];
    const float* Br = B[r];
    float acc = 0.0f;
#pragma unroll
    for (int j = 0; j < 16; j++) {
        float yj = Br[j];
#pragma unroll
        for (int k = 0; k < 16; k++) yj = fmaf(zs[k], Wr[k * 16 + j], yj);
        acc = fmaf(yj, zd[j], acc);
    }
    out[i] = acc;
}

// ---------------------------------------------------------------------------
extern "C" void kernel_launch(void* const* d_in, const int* in_sizes, int n_in,
                              void* d_out, int out_size, void* d_ws, size_t ws_size,
                              hipStream_t stream) {
    const float* x_paper = (const float*)d_in[0];
    const float* x_mesh  = (const float*)d_in[1];
    const int* tei  = (const int*)d_in[2];
    const int* tet  = (const int*)d_in[3];
    const int* pei  = (const int*)d_in[4];
    const int* pet  = (const int*)d_in[5];
    const int* nei  = (const int*)d_in[6];
    const int* net_ = (const int*)d_in[7];
    const float* Wp  = (const float*)d_in[8];
    const float* bp  = (const float*)d_in[9];
    const float* Wm  = (const float*)d_in[10];
    const float* bm  = (const float*)d_in[11];
    const float* Wd0 = (const float*)d_in[12];
    const float* bd0 = (const float*)d_in[13];
    const float* Wd1 = (const float*)d_in[14];
    const float* bd1 = (const float*)d_in[15];

    // Workspace carve-up (fp32 elements) — ~52 MB; pairs aliases aggbuf
    float* ws = (float*)d_ws;
    size_t o = 0;
    float* aggbuf = ws + o; o += (size_t)NN * 64; // [2][2][NN][16] fp32 = 23 MB
    unsigned short* xcA = (unsigned short*)(ws + o); o += (size_t)NN * 16; // sliced
    unsigned short* xcB = (unsigned short*)(ws + o); o += (size_t)NN * 16;
    unsigned short* zbf = (unsigned short*)(ws + o); o += (size_t)NN * 8;
    float* inv  = ws + o; o += (size_t)TWO_NN;
    int*   off  = (int*)(ws + o); o += (size_t)TWO_NN;
    int*   endo = (int*)(ws + o); o += (size_t)TWO_NN;
    int*   csr  = (int*)(ws + o); o += (size_t)NB_BKT * BKT_CAP;
    int*   gcur = (int*)(ws + o); o += 512;
    float* Wbuf4 = ws + o; o += 4 * 3200;
    int*   dflag = (int*)(ws + o); o += 16;
    int2*  pairs = (int2*)aggbuf; // 18 MB alias (dead before first gather)

    // 0. Init (gcur + dtype flag)
    init_kernel<<<(NB_BKT + 255) / 256, 256, 0, stream>>>(tei, gcur, dflag);

    // 1. Binned padded-bucket CSR build (once)
    binA_kernel<<<N_TILES, 256, 0, stream>>>(tei, tet, dflag, gcur, pairs);
    histplace_kernel<<<NB_BKT, 256, 0, stream>>>(gcur, pairs, off, endo, inv, csr);

    // 2. Fused embed -> xcA (sliced bf16, F=8)
    embed2_kernel<<<(NN + 255) / 256, 256, 0, stream>>>(
        x_paper, x_mesh, Wp, bp, Wm, bm, xcA);

    // 3. All layer weights in one launch
    prep_all_kernel<<<4, 256, 0, stream>>>(
        (const float*)d_in[16], (const float*)d_in[17], (const float*)d_in[18], (const float*)d_in[19],
        (const float*)d_in[20], (const float*)d_in[21], (const float*)d_in[22], (const float*)d_in[23],
        (const float*)d_in[24], (const float*)d_in[25], (const float*)d_in[26], (const float*)d_in[27],
        (const float*)d_in[28], (const float*)d_in[29], (const float*)d_in[30], (const float*)d_in[31],
        Wbuf4);

    // 4. Four RGCN layers: XCD-sliced gather -> dense combine
    int g16 = 8 * (((TWO_NN + 255) / 256 + 3) / 4); // DIN=16: GPB=256
    int g32 = 8 * (((TWO_NN + 127) / 128 + 3) / 4); // DIN=32: GPB=128
    int c32 = (NN + 31) / 32;                       // DOUT=32: NPB=32
    int c16 = (NN + 63) / 64;                       // DOUT=16: NPB=64

    gather_slice_kernel<16><<<g16, 256, 0, stream>>>(off, endo, csr, xcA, aggbuf);
    combine_kernel<16, 32, 1, 0><<<c32, 256, 0, stream>>>(xcA, aggbuf, inv,
                                                          Wbuf4 + 0 * 3200, xcB);
    gather_slice_kernel<32><<<g32, 256, 0, stream>>>(off, endo, csr, xcB, aggbuf);
    combine_kernel<32, 32, 1, 0><<<c32, 256, 0, stream>>>(xcB, aggbuf, inv,
                                                          Wbuf4 + 1 * 3200, xcA);
    gather_slice_kernel<32><<<g32, 256, 0, stream>>>(off, endo, csr, xcA, aggbuf);
    combine_kernel<32, 32, 1, 0><<<c32, 256, 0, stream>>>(xcA, aggbuf, inv,
                                                          Wbuf4 + 2 * 3200, xcB);
    gather_slice_kernel<32><<<g32, 256, 0, stream>>>(off, endo, csr, xcB, aggbuf);
    combine_kernel<32, 16, 0, 1><<<c16, 256, 0, stream>>>(xcB, aggbuf, inv,
                                                          Wbuf4 + 3 * 3200, zbf);

    // 5. Fused decode on bf16 z
    decode_fused_kernel<<<(2 * ED + 255) / 256, 256, 0, stream>>>(
        zbf, Wd0, bd0, Wd1, bd1, pei, pet, nei, net_, (float*)d_out, dflag);
}

// Round 18
// 375.435 us; speedup vs baseline: 1.1680x; 1.1680x over previous
//
#include <hip/hip_runtime.h>
#include <hip/hip_bf16.h>

// Problem constants (from reference)
constexpr int NN = 90000;   // total nodes
constexpr int NP = 60000;   // paper nodes
constexpr int NM = 30000;   // mesh nodes
constexpr int ET = 2000000; // train edges
constexpr int ED = 400000;  // decode edges (each of pos/neg)
constexpr int TWO_NN = 2 * NN;

// Binned CSR build parameters (512-key buckets for 2x block parallelism)
constexpr int BKT_SH  = 9;                           // 512 keys per bucket
constexpr int NB_BKT  = (TWO_NN + 511) >> BKT_SH;    // 352 buckets
constexpr int BKT_CAP = 6400;                        // mean 5683, +9.5 sigma
constexpr int TILE    = 2048;                        // edges per binning tile
constexpr int N_TILES = (ET + TILE - 1) / TILE;      // 977

__device__ __forceinline__ float bflo(unsigned int u) {
    union { unsigned int i; float f; } c;
    c.i = u << 16;
    return c.f;
}
__device__ __forceinline__ float bfhi(unsigned int u) {
    union { unsigned int i; float f; } c;
    c.i = u & 0xffff0000u;
    return c.f;
}
__device__ __forceinline__ unsigned short f2bf(float f) {
    union { float f; unsigned int i; } c;
    c.f = f;
    unsigned int x = c.i;
    return (unsigned short)((x + 0x7FFFu + ((x >> 16) & 1u)) >> 16);
}

// ---------------------------------------------------------------------------
// Init: gcur cursors + int32/int64 dtype flag (merged).
__global__ void init_kernel(const int* __restrict__ tei, int* __restrict__ gcur,
                            int* __restrict__ dflag) {
    int b = blockIdx.x * blockDim.x + threadIdx.x;
    if (b < NB_BKT) gcur[b] = b * BKT_CAP;
    if (b == 0) {
        int allzero = 1;
        for (int i = 0; i < 16; i++)
            if (tei[2 * i + 1] != 0) allzero = 0;
        dflag[0] = allzero; // 1 => int64 => index shift 1
    }
}

// ---------------------------------------------------------------------------
// Pass A: bin edges into per-bucket pair arrays with line-dense writes.
// Per-wave privatized histograms + placement cursors (R16).
__global__ void __launch_bounds__(256) binA_kernel(
        const int* __restrict__ ei, const int* __restrict__ et,
        const int* __restrict__ dflag, int* __restrict__ gcur,
        int2* __restrict__ pairs) {
    __shared__ int histw[4][NB_BKT];
    __shared__ int wbase[4][NB_BKT];
    __shared__ int tot[NB_BKT];
    __shared__ int excl[NB_BKT];
    __shared__ int gbase[NB_BKT];
    __shared__ int scn[256];
    __shared__ int2 tbuf[TILE];
    int t = threadIdx.x;
    int w = t >> 6; // wave id (4 waves of 64)
    int tile0 = blockIdx.x * TILE;
    int tcount = ET - tile0;
    if (tcount > TILE) tcount = TILE;
    for (int i = t; i < 4 * NB_BKT; i += 256) ((int*)histw)[i] = 0;
    __syncthreads();
    int sft = dflag[0];
    int myk[8], mys[8];
#pragma unroll
    for (int q = 0; q < 8; q++) {
        int li = q * 256 + t;
        myk[q] = -1;
        if (li < tcount) {
            int e = tile0 + li;
            int s = ei[(size_t)e << sft];
            int d = ei[(size_t)(ET + e) << sft];
            int r = et[(size_t)e << sft];
            int key = r * NN + d;
            myk[q] = key;
            mys[q] = s;
            atomicAdd(&histw[w][key >> BKT_SH], 1);
        }
    }
    __syncthreads();
    // combine per-wave histograms -> tot, per-wave placement offsets
    for (int i = t; i < NB_BKT; i += 256) {
        int h0 = histw[0][i], h1 = histw[1][i], h2 = histw[2][i], h3 = histw[3][i];
        wbase[0][i] = 0;
        wbase[1][i] = h0;
        wbase[2][i] = h0 + h1;
        wbase[3][i] = h0 + h1 + h2;
        tot[i] = h0 + h1 + h2 + h3;
    }
    __syncthreads();
    // exclusive scan of tot over 352 bins (2 bins per thread, t<176)
    int v0 = (t < NB_BKT / 2) ? tot[2 * t] : 0;
    int v1 = (t < NB_BKT / 2) ? tot[2 * t + 1] : 0;
    int s = v0 + v1;
    scn[t] = s;
    __syncthreads();
    for (int st = 1; st < 256; st <<= 1) {
        int u = (t >= st) ? scn[t - st] : 0;
        __syncthreads();
        scn[t] += u;
        __syncthreads();
    }
    int base = scn[t] - s;
    if (t < NB_BKT / 2) {
        excl[2 * t] = base;
        excl[2 * t + 1] = base + v0;
    }
    __syncthreads();
    // finalize per-wave bases; reset histw for reuse as placement cursors
    for (int i = t; i < NB_BKT; i += 256) {
        int e0 = excl[i];
        wbase[0][i] += e0;
        wbase[1][i] += e0;
        wbase[2][i] += e0;
        wbase[3][i] += e0;
        histw[0][i] = 0; histw[1][i] = 0; histw[2][i] = 0; histw[3][i] = 0;
    }
    __syncthreads();
    // place into LDS tile buffer (bucket-contiguous; per-wave cursor)
#pragma unroll
    for (int q = 0; q < 8; q++) {
        if (myk[q] >= 0) {
            int b = myk[q] >> BKT_SH;
            int p = wbase[w][b] + atomicAdd(&histw[w][b], 1);
            tbuf[p] = make_int2(myk[q], mys[q]);
        }
    }
    __syncthreads();
    // reserve global runs
    for (int i = t; i < NB_BKT; i += 256)
        if (tot[i] > 0) gbase[i] = atomicAdd(&gcur[i], tot[i]);
    __syncthreads();
    // flush: consecutive i -> mostly consecutive global positions
    for (int i = t; i < tcount; i += 256) {
        int2 p = tbuf[i];
        int b = p.x >> BKT_SH;
        int gpos = gbase[b] + (i - excl[b]);
        int cap = (b + 1) * BKT_CAP - 1;
        pairs[gpos < cap ? gpos : cap] = p;
    }
}

// ---------------------------------------------------------------------------
// Pass B (merged hist+place): per-bucket key histogram + block-local scan ->
// off/endo/inv, then place into padded CSR. 352 blocks (512 keys each).
__global__ void __launch_bounds__(256) histplace_kernel(
        const int* __restrict__ gcur, const int2* __restrict__ pairs,
        int* __restrict__ off, int* __restrict__ endo, float* __restrict__ inv,
        int* __restrict__ csr) {
    __shared__ int kh[512];
    __shared__ int scn[256];
    int b = blockIdx.x;
    int t = threadIdx.x;
    int beg = b * BKT_CAP, end = gcur[b];
    for (int i = t; i < 512; i += 256) kh[i] = 0;
    __syncthreads();
    for (int i = beg + t; i < end; i += 256)
        atomicAdd(&kh[pairs[i].x & 511], 1);
    __syncthreads();
    int v[2];
    int s = 0;
#pragma unroll
    for (int q = 0; q < 2; q++) {
        v[q] = kh[t * 2 + q];
        s += v[q];
    }
    scn[t] = s;
    __syncthreads();
    for (int st = 1; st < 256; st <<= 1) {
        int u = (t >= st) ? scn[t - st] : 0;
        __syncthreads();
        scn[t] += u;
        __syncthreads();
    }
    int run = beg + scn[t] - s;
    int kbase = b << BKT_SH;
    int kc[2];
#pragma unroll
    for (int q = 0; q < 2; q++) {
        int key = kbase + t * 2 + q;
        if (key < TWO_NN) {
            off[key] = run;
            endo[key] = run + v[q];
            inv[key] = 1.0f / (float)(v[q] > 1 ? v[q] : 1);
        }
        kc[q] = run;
        run += v[q];
    }
    __syncthreads();
#pragma unroll
    for (int q = 0; q < 2; q++) kh[t * 2 + q] = kc[q];
    __syncthreads();
    for (int i = beg + t; i < end; i += 256) {
        int2 p = pairs[i];
        int pos = atomicAdd(&kh[p.x & 511], 1);
        csr[pos] = p.y;
    }
}

// ---------------------------------------------------------------------------
// Fused input embed (paper+mesh): writes bf16 activations only.
__global__ void __launch_bounds__(256) embed2_kernel(
        const float* __restrict__ Xp, const float* __restrict__ Xm,
        const float* __restrict__ Wp, const float* __restrict__ bp,
        const float* __restrict__ Wm, const float* __restrict__ bm,
        unsigned short* __restrict__ outbf) {
    __shared__ float Wl[4096 + 32];
    for (int i = threadIdx.x; i < 2048; i += 256) {
        Wl[i] = Wp[i];
        Wl[2048 + i] = Wm[i];
    }
    if (threadIdx.x < 16) {
        Wl[4096 + threadIdx.x] = bp[threadIdx.x];
        Wl[4112 + threadIdx.x] = bm[threadIdx.x];
    }
    __syncthreads();
    int n = blockIdx.x * 256 + threadIdx.x;
    if (n >= NN) return;
    const float* X;
    const float* Ws;
    const float* Bs;
    if (n < NP) { X = Xp + (size_t)n * 128; Ws = Wl; Bs = Wl + 4096; }
    else        { X = Xm + (size_t)(n - NP) * 128; Ws = Wl + 2048; Bs = Wl + 4112; }
    float acc[16];
#pragma unroll
    for (int j = 0; j < 16; j++) acc[j] = Bs[j];
    const float4* row = (const float4*)X;
    for (int k4 = 0; k4 < 32; k4++) {
        float4 xv = row[k4];
        int k = k4 * 4;
#pragma unroll
        for (int j = 0; j < 16; j++) {
            float a = acc[j];
            a = fmaf(xv.x, Ws[(k + 0) * 16 + j], a);
            a = fmaf(xv.y, Ws[(k + 1) * 16 + j], a);
            a = fmaf(xv.z, Ws[(k + 2) * 16 + j], a);
            a = fmaf(xv.w, Ws[(k + 3) * 16 + j], a);
            acc[j] = a;
        }
    }
    ushort4* ob = (ushort4*)(outbf + (size_t)n * 16);
#pragma unroll
    for (int q = 0; q < 4; q++) {
        ushort4 ub;
        ub.x = f2bf(acc[4 * q]);     ub.y = f2bf(acc[4 * q + 1]);
        ub.z = f2bf(acc[4 * q + 2]); ub.w = f2bf(acc[4 * q + 3]);
        ob[q] = ub;
    }
}

// ---------------------------------------------------------------------------
// All 4 layers' weight prep in ONE launch: block l handles layer l.
// Wbuf4 layout per layer (stride 3200): [W0 | W1 | root | bias]
__global__ void prep_all_kernel(
        const float* __restrict__ ba0, const float* __restrict__ co0,
        const float* __restrict__ ro0, const float* __restrict__ bi0,
        const float* __restrict__ ba1, const float* __restrict__ co1,
        const float* __restrict__ ro1, const float* __restrict__ bi1,
        const float* __restrict__ ba2, const float* __restrict__ co2,
        const float* __restrict__ ro2, const float* __restrict__ bi2,
        const float* __restrict__ ba3, const float* __restrict__ co3,
        const float* __restrict__ ro3, const float* __restrict__ bi3,
        float* __restrict__ Wbuf4) {
    int l = blockIdx.x;
    const float* bases; const float* comp; const float* root; const float* bias;
    if (l == 0)      { bases = ba0; comp = co0; root = ro0; bias = bi0; }
    else if (l == 1) { bases = ba1; comp = co1; root = ro1; bias = bi1; }
    else if (l == 2) { bases = ba2; comp = co2; root = ro2; bias = bi2; }
    else             { bases = ba3; comp = co3; root = ro3; bias = bi3; }
    int din = (l == 0) ? 16 : 32;
    int dout = (l == 3) ? 16 : 32;
    int sz = din * dout;
    float* W = Wbuf4 + l * 3200;
    for (int i = threadIdx.x; i < sz; i += 256) {
        float b0 = bases[i];
        float b1 = bases[sz + i];
        float b2 = bases[2 * sz + i];
        float b3 = bases[3 * sz + i];
        for (int r = 0; r < 2; r++) {
            W[r * sz + i] = comp[r * 4 + 0] * b0 + comp[r * 4 + 1] * b1 +
                            comp[r * 4 + 2] * b2 + comp[r * 4 + 3] * b3;
        }
        W[2 * sz + i] = root[i];
    }
    if (threadIdx.x < dout) W[3 * sz + threadIdx.x] = bias[threadIdx.x];
}

// ---------------------------------------------------------------------------
// Fused RGCN layer, bf16-only activations (R13-R16: FETCH at compulsory floor;
// bound by random-line miss throughput — invariant under 4 restructurings).
// 16 B/lane gathers; combine from LDS; bf16 out.
template <int DIN, int DOUT, int RELU>
__global__ void __launch_bounds__(256) layer_kernel(
        const int* __restrict__ off, const int* __restrict__ endo,
        const int* __restrict__ csr,
        const unsigned short* __restrict__ xbf_in,
        const float* __restrict__ inv, const float* __restrict__ Wbuf,
        unsigned short* __restrict__ xbf_out) {
    constexpr int SZ = DIN * DOUT;
    constexpr int QL = DIN / 8;       // gather lanes per (node, rel): 16 B each
    constexpr int TPN = 2 * QL;       // phase-1 threads per node
    constexpr int NPB = 256 / TPN;    // nodes per block
    constexpr int AGST = 2 * DIN + 4; // agg LDS row stride
    constexpr int XSST = DIN + 4;     // xs LDS row stride
    __shared__ float Wl[3 * SZ + DOUT];
    __shared__ float agg[NPB * AGST];
    __shared__ float xs[NPB * XSST];
    for (int i = threadIdx.x; i < 3 * SZ + DOUT; i += 256) Wl[i] = Wbuf[i];
    int t = threadIdx.x;
    int ln = t / TPN;
    int rl = t % TPN;
    int r = rl / QL;
    int lane = rl % QL;
    int d = blockIdx.x * NPB + ln;
    if (d < NN) {
        if (r == 0) {
            uint4 u = *(const uint4*)(xbf_in + (size_t)d * DIN + lane * 8);
            float* xp = xs + ln * XSST + lane * 8;
            xp[0] = bflo(u.x); xp[1] = bfhi(u.x);
            xp[2] = bflo(u.y); xp[3] = bfhi(u.y);
            xp[4] = bflo(u.z); xp[5] = bfhi(u.z);
            xp[6] = bflo(u.w); xp[7] = bfhi(u.w);
        }
        int key = r * NN + d;
        int b = off[key];
        int e = endo[key];
        float a0[8] = {0, 0, 0, 0, 0, 0, 0, 0};
        float a1[8] = {0, 0, 0, 0, 0, 0, 0, 0};
        const unsigned short* hp = xbf_in + lane * 8;
        int k = b;
        for (; k + 1 < e; k += 2) {
            int s0 = csr[k];
            int s1 = csr[k + 1];
            uint4 u0 = *(const uint4*)(hp + (size_t)s0 * DIN);
            uint4 u1 = *(const uint4*)(hp + (size_t)s1 * DIN);
            a0[0] += bflo(u0.x); a0[1] += bfhi(u0.x);
            a0[2] += bflo(u0.y); a0[3] += bfhi(u0.y);
            a0[4] += bflo(u0.z); a0[5] += bfhi(u0.z);
            a0[6] += bflo(u0.w); a0[7] += bfhi(u0.w);
            a1[0] += bflo(u1.x); a1[1] += bfhi(u1.x);
            a1[2] += bflo(u1.y); a1[3] += bfhi(u1.y);
            a1[4] += bflo(u1.z); a1[5] += bfhi(u1.z);
            a1[6] += bflo(u1.w); a1[7] += bfhi(u1.w);
        }
        if (k < e) {
            uint4 u0 = *(const uint4*)(hp + (size_t)csr[k] * DIN);
            a0[0] += bflo(u0.x); a0[1] += bfhi(u0.x);
            a0[2] += bflo(u0.y); a0[3] += bfhi(u0.y);
            a0[4] += bflo(u0.z); a0[5] += bfhi(u0.z);
            a0[6] += bflo(u0.w); a0[7] += bfhi(u0.w);
        }
        float* ap = agg + ln * AGST + r * DIN + lane * 8;
        *(float4*)ap = make_float4(a0[0] + a1[0], a0[1] + a1[1],
                                   a0[2] + a1[2], a0[3] + a1[3]);
        *(float4*)(ap + 4) = make_float4(a0[4] + a1[4], a0[5] + a1[5],
                                         a0[6] + a1[6], a0[7] + a1[7]);
    }
    __syncthreads();
    constexpr int CPN = DOUT / 4;
    for (int tt = t; tt < NPB * CPN; tt += 256) {
        int ln2 = tt / CPN;
        int j0 = (tt % CPN) * 4;
        int d2 = blockIdx.x * NPB + ln2;
        if (d2 < NN) {
            float iv0 = inv[d2], iv1 = inv[NN + d2];
            float acc[4];
#pragma unroll
            for (int jj = 0; jj < 4; jj++) acc[jj] = Wl[3 * SZ + j0 + jj];
#pragma unroll
            for (int k = 0; k < DIN; k++) {
                float xv = xs[ln2 * XSST + k];
                float m0 = agg[ln2 * AGST + k] * iv0;
                float m1 = agg[ln2 * AGST + DIN + k] * iv1;
                const float* w0 = &Wl[k * DOUT + j0];
                const float* w1 = &Wl[SZ + k * DOUT + j0];
                const float* wr = &Wl[2 * SZ + k * DOUT + j0];
#pragma unroll
                for (int jj = 0; jj < 4; jj++) {
                    acc[jj] = fmaf(xv, wr[jj], acc[jj]);
                    acc[jj] = fmaf(m0, w0[jj], acc[jj]);
                    acc[jj] = fmaf(m1, w1[jj], acc[jj]);
                }
            }
            if (RELU) {
#pragma unroll
                for (int jj = 0; jj < 4; jj++) acc[jj] = fmaxf(acc[jj], 0.0f);
            }
            ushort4 ub;
            ub.x = f2bf(acc[0]); ub.y = f2bf(acc[1]);
            ub.z = f2bf(acc[2]); ub.w = f2bf(acc[3]);
            *(ushort4*)(xbf_out + (size_t)d2 * DOUT + j0) = ub;
        }
    }
}

// ---------------------------------------------------------------------------
// Fused decode on bf16 z: out[i] = dot( z[s]@Wd_r + bd_r , z[d] ).
__global__ void __launch_bounds__(256) decode_fused_kernel(
        const unsigned short* __restrict__ zbf,
        const float* __restrict__ Wd0, const float* __restrict__ bd0,
        const float* __restrict__ Wd1, const float* __restrict__ bd1,
        const int* __restrict__ pei, const int* __restrict__ pet,
        const int* __restrict__ nei, const int* __restrict__ net_,
        float* __restrict__ out, const int* __restrict__ dflag) {
    __shared__ float W[2][256];
    __shared__ float B[2][16];
    for (int i = threadIdx.x; i < 256; i += 256) {
        W[0][i] = Wd0[i];
        W[1][i] = Wd1[i];
    }
    if (threadIdx.x < 16) {
        B[0][threadIdx.x] = bd0[threadIdx.x];
        B[1][threadIdx.x] = bd1[threadIdx.x];
    }
    __syncthreads();
    int i = blockIdx.x * 256 + threadIdx.x;
    if (i >= 2 * ED) return;
    int sft = dflag[0];
    const int* ei;
    const int* et;
    int e;
    if (i < ED) { ei = pei; et = pet; e = i; }
    else        { ei = nei; et = net_; e = i - ED; }
    int s = ei[(size_t)e << sft];
    int d = ei[(size_t)(ED + e) << sft];
    int r = et[(size_t)e << sft];
    float zs[16], zd[16];
    const uint4* sp = (const uint4*)(zbf + ((size_t)s << 4));
    const uint4* dp = (const uint4*)(zbf + ((size_t)d << 4));
#pragma unroll
    for (int h = 0; h < 2; h++) {
        uint4 us = sp[h];
        uint4 ud = dp[h];
        int o8 = h * 8;
        zs[o8 + 0] = bflo(us.x); zs[o8 + 1] = bfhi(us.x);
        zs[o8 + 2] = bflo(us.y); zs[o8 + 3] = bfhi(us.y);
        zs[o8 + 4] = bflo(us.z); zs[o8 + 5] = bfhi(us.z);
        zs[o8 + 6] = bflo(us.w); zs[o8 + 7] = bfhi(us.w);
        zd[o8 + 0] = bflo(ud.x); zd[o8 + 1] = bfhi(ud.x);
        zd[o8 + 2] = bflo(ud.y); zd[o8 + 3] = bfhi(ud.y);
        zd[o8 + 4] = bflo(ud.z); zd[o8 + 5] = bfhi(ud.z);
        zd[o8 + 6] = bflo(ud.w); zd[o8 + 7] = bfhi(ud.w);
    }
    const float* Wr = W[r];
    const float* Br = B[r];
    float acc = 0.0f;
#pragma unroll
    for (int j = 0; j < 16; j++) {
        float yj = Br[j];
#pragma unroll
        for (int k = 0; k < 16; k++) yj = fmaf(zs[k], Wr[k * 16 + j], yj);
        acc = fmaf(yj, zd[j], acc);
    }
    out[i] = acc;
}

// ---------------------------------------------------------------------------
extern "C" void kernel_launch(void* const* d_in, const int* in_sizes, int n_in,
                              void* d_out, int out_size, void* d_ws, size_t ws_size,
                              hipStream_t stream) {
    const float* x_paper = (const float*)d_in[0];
    const float* x_mesh  = (const float*)d_in[1];
    const int* tei  = (const int*)d_in[2];
    const int* tet  = (const int*)d_in[3];
    const int* pei  = (const int*)d_in[4];
    const int* pet  = (const int*)d_in[5];
    const int* nei  = (const int*)d_in[6];
    const int* net_ = (const int*)d_in[7];
    const float* Wp  = (const float*)d_in[8];
    const float* bp  = (const float*)d_in[9];
    const float* Wm  = (const float*)d_in[10];
    const float* bm  = (const float*)d_in[11];
    const float* Wd0 = (const float*)d_in[12];
    const float* bd0 = (const float*)d_in[13];
    const float* Wd1 = (const float*)d_in[14];
    const float* bd1 = (const float*)d_in[15];

    // Workspace carve-up (fp32/int32 elements) — ~42 MB total
    float* ws = (float*)d_ws;
    size_t o = 0;
    unsigned short* xbfA = (unsigned short*)(ws + o); o += (size_t)NN * 16;
    unsigned short* xbfB = (unsigned short*)(ws + o); o += (size_t)NN * 16;
    float* inv  = ws + o; o += (size_t)TWO_NN;
    int*   off  = (int*)(ws + o); o += (size_t)TWO_NN;
    int*   endo = (int*)(ws + o); o += (size_t)TWO_NN;
    int*   csr  = (int*)(ws + o); o += (size_t)NB_BKT * BKT_CAP; // padded (9 MB)
    int*   gcur = (int*)(ws + o); o += 512;
    int2*  pairs = (int2*)(ws + o); o += (size_t)2 * NB_BKT * BKT_CAP; // 18 MB
    float* Wbuf4 = ws + o; o += 4 * 3200;
    int*   dflag = (int*)(ws + o); o += 16;

    // 0. Init (gcur + dtype flag)
    init_kernel<<<(NB_BKT + 255) / 256, 256, 0, stream>>>(tei, gcur, dflag);

    // 1. Binned padded-bucket CSR build (once)
    binA_kernel<<<N_TILES, 256, 0, stream>>>(tei, tet, dflag, gcur, pairs);
    histplace_kernel<<<NB_BKT, 256, 0, stream>>>(gcur, pairs, off, endo, inv, csr);

    // 2. Fused embed -> xbfA (bf16 only)
    embed2_kernel<<<(NN + 255) / 256, 256, 0, stream>>>(
        x_paper, x_mesh, Wp, bp, Wm, bm, xbfA);

    // 3. All layer weights in one launch
    prep_all_kernel<<<4, 256, 0, stream>>>(
        (const float*)d_in[16], (const float*)d_in[17], (const float*)d_in[18], (const float*)d_in[19],
        (const float*)d_in[20], (const float*)d_in[21], (const float*)d_in[22], (const float*)d_in[23],
        (const float*)d_in[24], (const float*)d_in[25], (const float*)d_in[26], (const float*)d_in[27],
        (const float*)d_in[28], (const float*)d_in[29], (const float*)d_in[30], (const float*)d_in[31],
        Wbuf4);

    // 4. Four fused RGCN layers, bf16 activations throughout
    int blk16 = (NN + 63) / 64; // DIN=16: NPB=64
    int blk32 = (NN + 31) / 32; // DIN=32: NPB=32
    layer_kernel<16, 32, 1><<<blk16, 256, 0, stream>>>(
        off, endo, csr, xbfA, inv, Wbuf4 + 0 * 3200, xbfB);
    layer_kernel<32, 32, 1><<<blk32, 256, 0, stream>>>(
        off, endo, csr, xbfB, inv, Wbuf4 + 1 * 3200, xbfA);
    layer_kernel<32, 32, 1><<<blk32, 256, 0, stream>>>(
        off, endo, csr, xbfA, inv, Wbuf4 + 2 * 3200, xbfB);
    layer_kernel<32, 16, 0><<<blk32, 256, 0, stream>>>(
        off, endo, csr, xbfB, inv, Wbuf4 + 3 * 3200, xbfA);
    // z (bf16) = xbfA [NN,16]

    // 5. Fused decode on bf16 z
    decode_fused_kernel<<<(2 * ED + 255) / 256, 256, 0, stream>>>(
        xbfA, Wd0, bd0, Wd1, bd1, pei, pet, nei, net_, (float*)d_out, dflag);
}